// Round 2
// baseline (4120.622 us; speedup 1.0000x reference)
//
#include <hip/hip_runtime.h>
#include <cstdint>

#define HDIM   1536
#define DIN    256
#define NSTEP  1008     // (T-1)*B = 63*16
#define NWG    256
#define TPB    384      // 6 waves; wave w owns unit g*6+w in BOTH layers
#define UPW    6
#define NREP   8        // exchange replicas

// Exchange: one 16-B self-tagged packet per producer WG per layer per parity.
// Packet = 2 x u64: u64_0 = v0|v1<<16|v2<<32|tag<<48, u64_1 = v3|v4<<16|v5<<32|tag<<48
// (6 bf16 h-values for units g*6..g*6+5; tag guards each u64 against tearing).
// u32 layout: region ((layer*2+par)*NREP+rep) of 1024 u32 (256 packets x 16B).
// Producer phase p: h0(p) -> parity p&1, tag p+1 ; h1(p-1) -> parity (p+1)&1, tag p+1.
// Consumer phase n: h0(n-1) at parity (n+1)&1 tag n ; h1(n-2) at parity n&1 tag n.
#define PKT_BASE_U32(layer, par, rep)  (((((layer)*2+(par))*NREP) + (rep)) << 10)
#define WS_FLAG_W 32768
#define PACE_MARGIN 1400
#define PACE_LEAK   24

typedef uint32_t u32x4v __attribute__((ext_vector_type(4)));

__device__ __forceinline__ float bflo(uint32_t p){ union{uint32_t u; float f;} v; v.u = p << 16; return v.f; }
__device__ __forceinline__ float bfhi(uint32_t p){ union{uint32_t u; float f;} v; v.u = p & 0xffff0000u; return v.f; }
__device__ __forceinline__ float bf2f(uint16_t b){ union{uint32_t u; float f;} v; v.u = ((uint32_t)b) << 16; return v.f; }
__device__ __forceinline__ uint16_t f2bf(float f){
    union{float f; uint32_t u;} v; v.f = f;
    uint32_t r = v.u + 0x7fffu + ((v.u >> 16) & 1u);   // RNE
    return (uint16_t)(r >> 16);
}
__device__ __forceinline__ uint32_t packbf(float lo, float hi){
    return (uint32_t)f2bf(lo) | ((uint32_t)f2bf(hi) << 16);
}
// inf-safe fast tanh: 1 - 2/(e^{2x}+1)
__device__ __forceinline__ float tanh_fast(float x){
    return 1.f - 2.f/(__expf(2.f*x) + 1.f);
}

#if __has_builtin(__builtin_amdgcn_fdot2_f32_bf16)
typedef __bf16 bf16x2 __attribute__((ext_vector_type(2)));
__device__ __forceinline__ float dot2bf(uint32_t a, uint32_t b, float c){
    return __builtin_amdgcn_fdot2_f32_bf16(__builtin_bit_cast(bf16x2, a),
                                           __builtin_bit_cast(bf16x2, b), c, false);
}
#else
__device__ __forceinline__ float dot2bf(uint32_t a, uint32_t b, float c){
    c = fmaf(bflo(a), bflo(b), c);
    c = fmaf(bfhi(a), bfhi(b), c);
    return c;
}
#endif

__device__ __forceinline__ float wave_sum(float x){
    #pragma unroll
    for (int o = 1; o < 64; o <<= 1) x += __shfl_xor(x, o, 64);
    return x;
}

// Paced poll of 4 packets (64 B) per lane covering all 256 producer WGs.
// On success, pr[12] = the 12 h-pairs (packets 4l..4l+3, 3 pairs each).
__device__ __forceinline__ void poll_gather(const uint32_t* base_u32, uint32_t want,
                                            int l, uint32_t pr[12],
                                            uint64_t& tprev, uint64_t& pmin, int n)
{
    const char* a = (const char*)base_u32 + 64*l;

    // pacing: sleep until just before the predicted arrival
    if (n >= 3 && pmin > 2500 && pmin < (1ull << 40)){
        const uint64_t tgt = tprev + pmin - PACE_MARGIN;
        uint64_t now = __builtin_readcyclecounter();
        while ((int64_t)(tgt - now) > 0){
            if (tgt - now > 4096) __builtin_amdgcn_s_sleep(16);
            else                  __builtin_amdgcn_s_sleep(2);
            now = __builtin_readcyclecounter();
        }
    }

    const uint32_t want2 = want | (want << 16);
    u32x4v q0, q1, q2, q3;
    for (;;){
        asm volatile(
            "global_load_dwordx4 %0, %4, off sc0 sc1\n\t"
            "global_load_dwordx4 %1, %4, off offset:16 sc0 sc1\n\t"
            "global_load_dwordx4 %2, %4, off offset:32 sc0 sc1\n\t"
            "global_load_dwordx4 %3, %4, off offset:48 sc0 sc1\n\t"
            "s_waitcnt vmcnt(0)"
            : "=v"(q0), "=v"(q1), "=v"(q2), "=v"(q3)
            : "v"(a) : "memory");
        uint32_t d;
        d  = __builtin_amdgcn_perm(q0.w, q0.y, 0x07060302u) ^ want2;
        d |= __builtin_amdgcn_perm(q1.w, q1.y, 0x07060302u) ^ want2;
        d |= __builtin_amdgcn_perm(q2.w, q2.y, 0x07060302u) ^ want2;
        d |= __builtin_amdgcn_perm(q3.w, q3.y, 0x07060302u) ^ want2;
        if (__all(d == 0u)) break;
        __builtin_amdgcn_s_sleep(1);
    }
    const uint64_t tdisc = __builtin_readcyclecounter();
    if (n >= 1){
        const uint64_t iv = tdisc - tprev;
        if (iv < pmin) pmin = iv;
        else if (pmin < (1ull << 40)) pmin += PACE_LEAK;
    }
    tprev = tdisc;

    // extract 12 pairs: per packet {x,y,z,w}: p0=x, p1={y.lo,z.lo}, p2={z.hi,w.lo}
    pr[0]  = q0.x;
    pr[1]  = __builtin_amdgcn_perm(q0.z, q0.y, 0x05040100u);
    pr[2]  = __builtin_amdgcn_perm(q0.w, q0.z, 0x05040302u);
    pr[3]  = q1.x;
    pr[4]  = __builtin_amdgcn_perm(q1.z, q1.y, 0x05040100u);
    pr[5]  = __builtin_amdgcn_perm(q1.w, q1.z, 0x05040302u);
    pr[6]  = q2.x;
    pr[7]  = __builtin_amdgcn_perm(q2.z, q2.y, 0x05040100u);
    pr[8]  = __builtin_amdgcn_perm(q2.w, q2.z, 0x05040302u);
    pr[9]  = q3.x;
    pr[10] = __builtin_amdgcn_perm(q3.z, q3.y, 0x05040100u);
    pr[11] = __builtin_amdgcn_perm(q3.w, q3.z, 0x05040302u);
}

// ---------------------------------------------------------------------------
// init kernel: clear exchange, seed boot tags, dtype probe
// ---------------------------------------------------------------------------
__global__ void init_ws(const uint32_t* __restrict__ w, uint32_t* __restrict__ ws){
    const int i = blockIdx.x * blockDim.x + threadIdx.x;
    if (i < 4*NREP*1024){
        const int region = i >> 13;          // (layer*2+par): 1024*NREP u32 per region
        uint32_t v = 0u;
        if (region == 3) v = (i & 1) ? 0x00010000u : 0u;   // h1 par1: tag 1, zeros
        ws[i] = v;   // h0 par1 & h1 par0: tag 0 zeros; others don't-care (0)
    }
    if (blockIdx.x == 0 && threadIdx.x < 64){
        const int t = threadIdx.x;
        int cnt = 0;
        #pragma unroll
        for (int j = 0; j < 4; ++j){
            const uint32_t v = w[t*4 + j];
            const uint32_t e = (v >> 7) & 0xFFu;
            if (e == 0u || (e >= 0x70u && e <= 0x7Cu)) cnt++;
        }
        #pragma unroll
        for (int o = 1; o < 64; o <<= 1) cnt += __shfl_xor(cnt, o, 64);
        if (t == 0)
            ws[WS_FLAG_W] = (cnt < 128) ? 1u : 0u;   // sparse in-window => fp32
    }
}

__global__ __launch_bounds__(TPB, 1)
void lstm_seq_kernel(const void* __restrict__ batch_,
                     const void* __restrict__ Wih0_,
                     const void* __restrict__ Whh0_,
                     const void* __restrict__ bih0_,
                     const void* __restrict__ bhh0_,
                     const void* __restrict__ Wih1_,
                     const void* __restrict__ Whh1_,
                     const void* __restrict__ bih1_,
                     const void* __restrict__ bhh1_,
                     void* __restrict__ out_,
                     uint32_t* __restrict__ ws)
{
    __shared__ uint32_t lds_w[UPW*4*8*64];   // L1 chunks 0..7 per owned row
    __shared__ uint32_t lds_h0[768];         // packed h0 pairs (wave0-written)
    __shared__ uint32_t lds_h1[768];         // packed h1 pairs (wave1-written)
    __shared__ uint32_t lds_pack[2][8];      // per-wave bf16 h values for packing
    __shared__ uint32_t lds_cnt[2];          // monotonic pack arrival counters
    __shared__ int      lds_flag[2];

    const int g   = blockIdx.x;
    const int tid = threadIdx.x;
    const int w   = tid >> 6;        // wave 0..5
    const int l   = tid & 63;
    const int U   = g*UPW + w;       // owned hidden unit (both layers)
    const int rep = g & (NREP-1);

    const uint32_t fp32in = __hip_atomic_load(&ws[WS_FLAG_W],
                             __ATOMIC_RELAXED, __HIP_MEMORY_SCOPE_AGENT);

    if (tid < 2){ lds_flag[tid] = -1; lds_cnt[tid] = 0u; }

    // ---------------- persistent weight load (once) ----------------
    uint32_t w0[4][14];   // L0 rows of unit U: 2 x-chunks + 12 h-chunks
    uint32_t w1[4][16];   // L1 rows: chunks 8..11 (W_ih1) + 12..23 (W_hh1)
    float bb0[4], bb1[4];

    if (fp32in){
        const float2* Wih0f = (const float2*)Wih0_;
        const float2* Whh0f = (const float2*)Whh0_;
        const float2* Wih1f = (const float2*)Wih1_;
        const float2* Whh1f = (const float2*)Whh1_;
        #pragma unroll
        for (int r = 0; r < 4; ++r){
            const int grow = r*HDIM + U;
            float2 t;
            t = Wih0f[grow*(DIN/2) + l];      w0[r][0] = packbf(t.x, t.y);
            t = Wih0f[grow*(DIN/2) + 64 + l]; w0[r][1] = packbf(t.x, t.y);
            #pragma unroll
            for (int c = 0; c < 12; ++c){
                t = Whh0f[grow*(HDIM/2) + c*64 + l]; w0[r][c+2] = packbf(t.x, t.y);
            }
            #pragma unroll
            for (int c = 0; c < 8; ++c){
                t = Wih1f[grow*(HDIM/2) + c*64 + l];
                lds_w[(w*4 + r)*512 + c*64 + l] = packbf(t.x, t.y);
            }
            #pragma unroll
            for (int c = 8; c < 12; ++c){
                t = Wih1f[grow*(HDIM/2) + c*64 + l]; w1[r][c-8] = packbf(t.x, t.y);
            }
            #pragma unroll
            for (int c = 0; c < 12; ++c){
                t = Whh1f[grow*(HDIM/2) + c*64 + l]; w1[r][c+4] = packbf(t.x, t.y);
            }
            bb0[r] = ((const float*)bih0_)[grow] + ((const float*)bhh0_)[grow];
            bb1[r] = ((const float*)bih1_)[grow] + ((const float*)bhh1_)[grow];
        }
    } else {
        const uint32_t* Wih0p = (const uint32_t*)Wih0_;
        const uint32_t* Whh0p = (const uint32_t*)Whh0_;
        const uint32_t* Wih1p = (const uint32_t*)Wih1_;
        const uint32_t* Whh1p = (const uint32_t*)Whh1_;
        #pragma unroll
        for (int r = 0; r < 4; ++r){
            const int grow = r*HDIM + U;
            w0[r][0] = Wih0p[grow*(DIN/2) + l];
            w0[r][1] = Wih0p[grow*(DIN/2) + 64 + l];
            #pragma unroll
            for (int c = 0; c < 12; ++c) w0[r][c+2] = Whh0p[grow*(HDIM/2) + c*64 + l];
            #pragma unroll
            for (int c = 0; c < 8; ++c)
                lds_w[(w*4 + r)*512 + c*64 + l] = Wih1p[grow*(HDIM/2) + c*64 + l];
            #pragma unroll
            for (int c = 8; c < 12; ++c) w1[r][c-8] = Wih1p[grow*(HDIM/2) + c*64 + l];
            #pragma unroll
            for (int c = 0; c < 12; ++c) w1[r][c+4] = Whh1p[grow*(HDIM/2) + c*64 + l];
            bb0[r] = bf2f(((const uint16_t*)bih0_)[grow]) + bf2f(((const uint16_t*)bhh0_)[grow]);
            bb1[r] = bf2f(((const uint16_t*)bih1_)[grow]) + bf2f(((const uint16_t*)bhh1_)[grow]);
        }
    }
    __syncthreads();   // lds_flag/cnt init + lds_w ready; no barriers in main loop

    float c0 = 0.f, c1 = 0.f, h0f = 0.f, h1f = 0.f;
    uint64_t t0 = 0, p0 = 1ull << 60;   // wave0 pacing state (h0)
    uint64_t t1 = 0, p1 = 1ull << 60;   // wave1 pacing state (h1)

    for (int n = 0; n <= NSTEP; ++n){
        // x prefetch (issued before any spinning)
        uint32_t xp0 = 0, xp1 = 0;
        if (n < NSTEP){
            const int xbase = ((n & 15)*64 + (n >> 4) + 1) * DIN;
            if (fp32in){
                const float2* bp = (const float2*)((const float*)batch_ + xbase);
                const float2 q0 = bp[l];
                const float2 q1 = bp[64 + l];
                xp0 = packbf(q0.x, q0.y); xp1 = packbf(q1.x, q1.y);
            } else {
                const uint32_t* bp = (const uint32_t*)batch_ + (xbase >> 1);
                xp0 = bp[l]; xp1 = bp[64 + l];
            }
        }

        uint32_t h0p[12];
        uint32_t h1p[12];

        // wave 1: h1 ingest (published a full phase ago -> ~1 sweep)
        if (w == 1 && n >= 1){
            uint32_t pr[12];
            poll_gather(ws + PKT_BASE_U32(1, n & 1, rep), (uint32_t)n, l, pr, t1, p1, n);
            #pragma unroll
            for (int k = 0; k < 12; ++k) lds_h1[12*l + k] = pr[k];
            __hip_atomic_store(&lds_flag[1], n, __ATOMIC_RELEASE, __HIP_MEMORY_SCOPE_WORKGROUP);
        }

        // h0 ingest: wave 0 polls LLC, others take LDS rebroadcast
        if (w == 0){
            uint32_t pr[12];
            poll_gather(ws + PKT_BASE_U32(0, (n+1) & 1, rep), (uint32_t)n, l, pr, t0, p0, n);
            #pragma unroll
            for (int k = 0; k < 12; ++k) lds_h0[12*l + k] = pr[k];
            __hip_atomic_store(&lds_flag[0], n, __ATOMIC_RELEASE, __HIP_MEMORY_SCOPE_WORKGROUP);
            #pragma unroll
            for (int k = 0; k < 12; ++k) h0p[k] = lds_h0[k*64 + l];
        } else {
            while (__hip_atomic_load(&lds_flag[0], __ATOMIC_ACQUIRE, __HIP_MEMORY_SCOPE_WORKGROUP) < n)
                __builtin_amdgcn_s_sleep(1);
            #pragma unroll
            for (int k = 0; k < 12; ++k) h0p[k] = lds_h0[k*64 + l];
        }

        // ---------------- layer 0 (the critical recurrence) ----------------
        if (n < NSTEP){
            __builtin_amdgcn_s_setprio(1);
            float acc[4];
            #pragma unroll
            for (int r = 0; r < 4; ++r){
                float a = dot2bf(w0[r][0], xp0, 0.f);
                a = dot2bf(w0[r][1], xp1, a);
                #pragma unroll
                for (int k = 0; k < 12; ++k) a = dot2bf(w0[r][k+2], h0p[k], a);
                acc[r] = a;
            }
            #pragma unroll
            for (int r = 0; r < 4; ++r) acc[r] = wave_sum(acc[r]);
            const float gi = acc[0] + bb0[0];
            const float gf = acc[1] + bb0[1];
            const float gg = acc[2] + bb0[2];
            const float go = acc[3] + bb0[3];
            const float si = 1.f/(1.f + __expf(-gi));
            const float sf = 1.f/(1.f + __expf(-gf));
            const float so = 1.f/(1.f + __expf(-go));
            c0  = sf*c0 + si*tanh_fast(gg);
            h0f = so*tanh_fast(c0);
            __builtin_amdgcn_s_setprio(0);
            // packet publish: last-arriving wave packs 6 values + tag, 2 u64 stores/replica
            if (l == 0){
                lds_pack[0][w] = (uint32_t)f2bf(h0f);
                const uint32_t old = __hip_atomic_fetch_add(&lds_cnt[0], 1u,
                                        __ATOMIC_ACQ_REL, __HIP_MEMORY_SCOPE_WORKGROUP);
                if (old == 6u*(uint32_t)n + 5u){
                    const uint64_t tag = (uint64_t)(uint32_t)(n + 1) << 48;
                    const uint64_t pk0 = (uint64_t)lds_pack[0][0]
                                       | ((uint64_t)lds_pack[0][1] << 16)
                                       | ((uint64_t)lds_pack[0][2] << 32) | tag;
                    const uint64_t pk1 = (uint64_t)lds_pack[0][3]
                                       | ((uint64_t)lds_pack[0][4] << 16)
                                       | ((uint64_t)lds_pack[0][5] << 32) | tag;
                    #pragma unroll
                    for (int rp = 0; rp < NREP; ++rp){
                        uint64_t* d = (uint64_t*)ws
                            + ((uint64_t)(PKT_BASE_U32(0, n & 1, rp)) >> 1) + 2*g;
                        __hip_atomic_store(d,   pk0, __ATOMIC_RELAXED, __HIP_MEMORY_SCOPE_AGENT);
                        __hip_atomic_store(d+1, pk1, __ATOMIC_RELAXED, __HIP_MEMORY_SCOPE_AGENT);
                    }
                }
            }
        }

        // ---------------- layer 1 (trails with a phase of slack) ----------------
        if (n >= 1){
            if (w != 1){
                while (__hip_atomic_load(&lds_flag[1], __ATOMIC_ACQUIRE, __HIP_MEMORY_SCOPE_WORKGROUP) < n)
                    __builtin_amdgcn_s_sleep(1);
            }
            #pragma unroll
            for (int k = 0; k < 12; ++k) h1p[k] = lds_h1[k*64 + l];
            float acc[4];
            #pragma unroll
            for (int r = 0; r < 4; ++r){
                float a = 0.f;
                #pragma unroll
                for (int c = 0; c < 8; ++c)
                    a = dot2bf(lds_w[(w*4 + r)*512 + c*64 + l], h0p[c], a);
                #pragma unroll
                for (int c = 8; c < 12; ++c) a = dot2bf(w1[r][c-8], h0p[c], a);
                #pragma unroll
                for (int k = 0; k < 12; ++k) a = dot2bf(w1[r][k+4], h1p[k], a);
                acc[r] = a;
            }
            #pragma unroll
            for (int r = 0; r < 4; ++r) acc[r] = wave_sum(acc[r]);
            const float gi = acc[0] + bb1[0];
            const float gf = acc[1] + bb1[1];
            const float gg = acc[2] + bb1[2];
            const float go = acc[3] + bb1[3];
            const float si = 1.f/(1.f + __expf(-gi));
            const float sf = 1.f/(1.f + __expf(-gf));
            const float so = 1.f/(1.f + __expf(-go));
            c1  = sf*c1 + si*tanh_fast(gg);
            h1f = so*tanh_fast(c1);
            if (n < NSTEP && l == 0){
                lds_pack[1][w] = (uint32_t)f2bf(h1f);
                const uint32_t old = __hip_atomic_fetch_add(&lds_cnt[1], 1u,
                                        __ATOMIC_ACQ_REL, __HIP_MEMORY_SCOPE_WORKGROUP);
                if (old == 6u*(uint32_t)(n - 1) + 5u){
                    const uint64_t tag = (uint64_t)(uint32_t)(n + 1) << 48;
                    const uint64_t pk0 = (uint64_t)lds_pack[1][0]
                                       | ((uint64_t)lds_pack[1][1] << 16)
                                       | ((uint64_t)lds_pack[1][2] << 32) | tag;
                    const uint64_t pk1 = (uint64_t)lds_pack[1][3]
                                       | ((uint64_t)lds_pack[1][4] << 16)
                                       | ((uint64_t)lds_pack[1][5] << 32) | tag;
                    #pragma unroll
                    for (int rp = 0; rp < NREP; ++rp){
                        uint64_t* d = (uint64_t*)ws
                            + ((uint64_t)(PKT_BASE_U32(1, (n+1) & 1, rp)) >> 1) + 2*g;
                        __hip_atomic_store(d,   pk0, __ATOMIC_RELAXED, __HIP_MEMORY_SCOPE_AGENT);
                        __hip_atomic_store(d+1, pk1, __ATOMIC_RELAXED, __HIP_MEMORY_SCOPE_AGENT);
                    }
                }
            }
        }
    }

    // ---------------- output: h[2][1536] ++ c[2][1536] ----------------
    if (l == 0){
        if (fp32in){
            float* o = (float*)out_;
            o[U]               = h0f;
            o[HDIM + U]        = h1f;
            o[3072 + U]        = c0;
            o[3072 + HDIM + U] = c1;
        } else {
            uint16_t* o = (uint16_t*)out_;
            o[U]               = f2bf(h0f);
            o[HDIM + U]        = f2bf(h1f);
            o[3072 + U]        = f2bf(c0);
            o[3072 + HDIM + U] = f2bf(c1);
        }
    }
}

extern "C" void kernel_launch(void* const* d_in, const int* in_sizes, int n_in,
                              void* d_out, int out_size, void* d_ws, size_t ws_size,
                              hipStream_t stream)
{
    (void)in_sizes; (void)n_in; (void)out_size; (void)ws_size;
    const void* batch = d_in[0];
    const void* Wih0  = d_in[1];
    const void* Whh0  = d_in[2];
    const void* bih0  = d_in[3];
    const void* bhh0  = d_in[4];
    const void* Wih1  = d_in[5];
    const void* Whh1  = d_in[6];
    const void* bih1  = d_in[7];
    const void* bhh1  = d_in[8];
    void* out = d_out;
    uint32_t* ws = (uint32_t*)d_ws;

    hipLaunchKernelGGL(init_ws, dim3((4*NREP*1024 + 255)/256), dim3(256), 0, stream,
                       (const uint32_t*)Whh0, ws);

    void* args[] = { &batch, &Wih0, &Whh0, &bih0, &bhh0,
                     &Wih1, &Whh1, &bih1, &bhh1, &out, &ws };
    hipLaunchCooperativeKernel((const void*)lstm_seq_kernel,
                               dim3(NWG), dim3(TPB), args, 0, stream);
}